// Round 17
// baseline (660.737 us; speedup 1.0000x reference)
//
#include <hip/hip_runtime.h>
#include <hip/hip_bf16.h>
#include <stdint.h>

typedef __bf16 bf16x8 __attribute__((ext_vector_type(8)));
typedef float  f32x4  __attribute__((ext_vector_type(4)));

#define NATOMS  32768
#define NEXP    4
#define MAXROWS (NATOMS + NEXP*256)   // 33792
#define MB256   (MAXROWS/256)         // 132
#define MB128   (MAXROWS/128)         // 264
#define MGRP    ((MB256 + 7)/8)       // 17
#define XCONV   2048                  // convert blocks: 1024 thr x 16 f32
#define SCAT    32                    // scatter blocks: 1024 thr x 1 atom

// ---------------- ws layout (bytes) ----------------
#define WS_HDR   0u
#define WS_PERM  1024u                        // int[33792] = 135168 -> ends 136192
#define WS_BC    136192u                      // int[128][4] = 2048
#define WS_BB    138240u                      // int[128][4] = 2048
#define WS_W1T   140288u                      // [4][512][1024] bf16 = 4194304
#define WS_W2T   (WS_W1T + 4194304u)
#define WS_W3T   (WS_W2T + 524288u)
#define WS_W4T   (WS_W3T + 524288u)
#define WS_H     (WS_W4T + 4194304u)          // [33792][512] bf16 = 34603008
#define WS_XB    (WS_H + 34603008u)           // [32768][1024] bf16 = 67108864
// total ~111.3 MB

__device__ __forceinline__ unsigned short f2bf(float f){
  union { float f; uint32_t u; } v; v.f = f;
  uint32_t r = v.u + 0x7fffu + ((v.u >> 16) & 1u);   // RNE
  return (unsigned short)(r >> 16);
}
__device__ __forceinline__ uint32_t pk2(float a, float b){
  return (uint32_t)f2bf(a) | ((uint32_t)f2bf(b) << 16);
}
__device__ __forceinline__ void glds16(const void* g, void* l){
  __builtin_amdgcn_global_load_lds(
      (const __attribute__((address_space(1))) uint32_t*)g,
      (__attribute__((address_space(3))) uint32_t*)l, 16, 0, 0);
}

// ---------------- routeA: per-block histogram + perm pad-fill ----------------
__global__ __launch_bounds__(256) void routeA(const int* __restrict__ sym,
                                              int* __restrict__ bc,
                                              int* __restrict__ perm){
  __shared__ int h[NEXP];
  const int t = threadIdx.x, b = blockIdx.x;
  if (t < NEXP) h[t] = 0;
  for (int i = b*256 + t; i < MAXROWS; i += 128*256) perm[i] = -1;
  __syncthreads();
  int s = sym[b*256 + t];
  atomicAdd(&h[s], 1);
  __syncthreads();
  if (t < NEXP) bc[b*NEXP + t] = h[t];
}

// ---------------- routeB: scan block counts -> bases + hdr ----------------
__global__ __launch_bounds__(64) void routeB(const int* __restrict__ bc,
                                             int* __restrict__ hdr,
                                             int* __restrict__ bb){
  __shared__ int tot[NEXP], pof[NEXP+1];
  const int t = threadIdx.x;
  if (t < NEXP){
    int s = 0;
    for (int i=0;i<128;++i) s += bc[i*NEXP + t];
    tot[t] = s;
  }
  __syncthreads();
  if (t == 0){
    int o = 0; pof[0] = 0;
    for (int e=0;e<NEXP;++e){ o += (tot[e]+255)&~255; pof[e+1]=o; }
    for (int e=0;e<=NEXP;++e) hdr[e]=pof[e];
  }
  __syncthreads();
  if (t < NEXP){
    int run = pof[t];
    for (int i=0;i<128;++i){ bb[i*NEXP + t] = run; run += bc[i*NEXP + t]; }
  }
}

// ---------------- weight transpose helper (1024 threads) ----------------
template<int K, int NO>
__device__ __forceinline__ void wtile1024(const float* __restrict__ W,
                                          unsigned short* __restrict__ Bt,
                                          int b, unsigned short (*tile)[65]){
  const int nx = NO/64, ny = K/64;
  const int e = b / (nx*ny), rem = b % (nx*ny);
  const int k0 = (rem / nx) * 64;
  const int n0 = (rem % nx) * 64;
  const int t  = threadIdx.x;
  const int c  = t & 63;
  const float* Wb = W + ((size_t)e*K + k0)*NO + n0;
  #pragma unroll
  for (int i=0;i<4;++i){
    int r = (t>>6) + i*16;
    tile[r][c] = f2bf(Wb[(size_t)r*NO + c]);
  }
  __syncthreads();
  unsigned short* Bb = Bt + ((size_t)e*NO + n0)*K + k0;
  #pragma unroll
  for (int i=0;i<4;++i){
    int r = (t>>6) + i*16;
    Bb[(size_t)r*K + c] = tile[c][r];
  }
}

// ---------------- prep: scatter + X convert + weight transposes (R15-proven) ----------------
__global__ __launch_bounds__(1024) void prep_kernel(
    const int*   __restrict__ sym,  const int* __restrict__ bb,  int* __restrict__ perm,
    const float* __restrict__ X,    unsigned short* __restrict__ Xb,
    const float* __restrict__ We1, unsigned short* __restrict__ W1t,
    const float* __restrict__ We2, unsigned short* __restrict__ W2t,
    const float* __restrict__ Wd1, unsigned short* __restrict__ W3t,
    const float* __restrict__ Wd2, unsigned short* __restrict__ W4t)
{
  __shared__ unsigned short tile[64][65];
  __shared__ int wc[16][NEXP];

  int b = blockIdx.x;
  const int t = threadIdx.x;

  if (b < SCAT){
    // ---- stable parallel scatter: 1 atom/thread ----
    const int lane = t & 63, w = t >> 6;
    const int a = b*1024 + t;
    const int s = sym[a];
    unsigned long long b0 = __ballot(s & 1);
    unsigned long long b1 = __ballot(s & 2);
    unsigned long long meq = ((s & 1) ? b0 : ~b0) & ((s & 2) ? b1 : ~b1);
    unsigned long long lt  = ((unsigned long long)1 << lane) - 1;
    const int lofs = __popcll(meq & lt);
    if (lane == 0){
      unsigned long long m00 = ~b0 & ~b1, m01 = b0 & ~b1, m10 = ~b0 & b1, m11 = b0 & b1;
      wc[w][0] = __popcll(m00); wc[w][1] = __popcll(m01);
      wc[w][2] = __popcll(m10); wc[w][3] = __popcll(m11);
    }
    __syncthreads();
    const int rb = (t >> 8);          // which 256-atom sub-block (0..3)
    int wbase_rb = 0;
    for (int i = rb*4; i < w; ++i) wbase_rb += wc[i][s];
    const int slot = bb[(b*4 + rb)*NEXP + s] + wbase_rb + lofs;
    perm[slot] = a;
    return;
  }
  b -= SCAT;
  if (b < XCONV){
    // ---- linear X convert: 16 floats/thread ----
    size_t i = ((size_t)b*1024 + t) * 16;
    const float4* src = (const float4*)(X + i);
    float4 f0 = src[0], f1 = src[1], f2 = src[2], f3 = src[3];
    uint4 o0, o1;
    o0.x = pk2(f0.x,f0.y); o0.y = pk2(f0.z,f0.w);
    o0.z = pk2(f1.x,f1.y); o0.w = pk2(f1.z,f1.w);
    o1.x = pk2(f2.x,f2.y); o1.y = pk2(f2.z,f2.w);
    o1.z = pk2(f3.x,f3.y); o1.w = pk2(f3.z,f3.w);
    *(uint4*)&Xb[i]     = o0;
    *(uint4*)&Xb[i + 8] = o1;
    return;
  }
  b -= XCONV;
  if (b < 512){ wtile1024<1024, 512>(We1, W1t, b, tile); return; }
  b -= 512;
  if (b <  64){ wtile1024< 512, 128>(We2, W2t, b, tile); return; }
  b -= 64;
  if (b <  64){ wtile1024< 128, 512>(Wd1, W3t, b, tile); return; }
  b -= 64;
  wtile1024< 512,1024>(Wd2, W4t, b, tile);
}

// ---------------- L1: 256x128 tile MFMA GEMM, 8 waves (4x2), BK=64 (R6-proven) ----------------
template<int K, int NO, int NT, bool RELU, bool GATHER>
__global__ __launch_bounds__(512, 4) void gemm_big(
    const unsigned short* __restrict__ A,
    const unsigned short* __restrict__ Bt,
    const float* __restrict__ bias,
    unsigned short* __restrict__ Cb,
    const int* __restrict__ hdr,
    const int* __restrict__ perm)
{
  __shared__ __align__(16) unsigned short smem[256*64 + 128*64];  // 48 KB
  __shared__ int sperm[256];
  unsigned short* As = smem;             // [256][64] linear, source-swizzled
  unsigned short* Bs = smem + 256*64;    // [128][64]

  const int b = blockIdx.x;
  const int grp = b / (8*NT), rem = b % (8*NT);
  const int rowblk = grp*8 + (rem & 7);
  const int row0 = rowblk * 256;
  if (row0 >= hdr[NEXP]) return;
  const int ntile = rem >> 3;
  const int e = (row0 >= hdr[1]) + (row0 >= hdr[2]) + (row0 >= hdr[3]);
  const int n0 = ntile * 128;

  const int t = threadIdx.x;
  const int lane = t & 63, wid = t >> 6;

  if constexpr (GATHER){
    if (t < 256) sperm[t] = perm[row0 + t];
    __syncthreads();
  }

  const int l8 = lane >> 3;
  const int scoff = (((lane & 7) ^ l8) << 3);   // swizzled source chunk (shorts)

  const unsigned short* asrc[4];
  #pragma unroll
  for (int i=0;i<4;++i){
    const int r = wid*32 + i*8 + l8;
    long grow;
    if constexpr (GATHER){
      int a = sperm[r];
      grow = (a < 0) ? 0 : a;
    } else {
      grow = row0 + r;
    }
    asrc[i] = A + (size_t)grow*K + scoff;
  }
  const unsigned short* bsrc[2];
  #pragma unroll
  for (int i=0;i<2;++i)
    bsrc[i] = Bt + ((size_t)e*NO + n0 + wid*16 + i*8 + l8)*K + scoff;

  const int lr   = lane & 15;
  const int sgrp = lane >> 4;
  const int wr   = (wid >> 1) * 64;
  const int wc   = (wid & 1) * 64;

  f32x4 acc[4][4];
  const f32x4 z4 = {0.f,0.f,0.f,0.f};
  #pragma unroll
  for (int mi=0;mi<4;++mi)
    #pragma unroll
    for (int ni=0;ni<4;++ni) acc[mi][ni] = z4;

  #pragma unroll 1
  for (int kt = 0; kt < K/64; ++kt){
    __syncthreads();
    #pragma unroll
    for (int i=0;i<4;++i)
      glds16(asrc[i] + kt*64, As + (wid*4+i)*512);
    #pragma unroll
    for (int i=0;i<2;++i)
      glds16(bsrc[i] + kt*64, Bs + (wid*2+i)*512);
    __syncthreads();

    #pragma unroll
    for (int kk=0;kk<2;++kk){
      bf16x8 af[4], bfr[4];
      const int s = kk*4 + sgrp;
      #pragma unroll
      for (int mi=0;mi<4;++mi){
        int R = wr + mi*16 + lr;
        af[mi] = *(const bf16x8*)&As[R*64 + ((s ^ (R & 7)) << 3)];
      }
      #pragma unroll
      for (int ni=0;ni<4;++ni){
        int Cc = wc + ni*16 + lr;
        bfr[ni] = *(const bf16x8*)&Bs[Cc*64 + ((s ^ (Cc & 7)) << 3)];
      }
      #pragma unroll
      for (int mi=0;mi<4;++mi)
        #pragma unroll
        for (int ni=0;ni<4;++ni)
          acc[mi][ni] = __builtin_amdgcn_mfma_f32_16x16x32_bf16(af[mi], bfr[ni], acc[mi][ni], 0, 0, 0);
    }
  }

  // epilogue: LDS-staged bf16, full-line row writes
  __syncthreads();
  unsigned short* st = smem;          // [128][136] bf16
  const int wrl = ((wid >> 1) & 1) * 64;
  #pragma unroll
  for (int h=0; h<2; ++h){
    if ((wid >> 2) == h){
      #pragma unroll
      for (int ni=0;ni<4;++ni){
        const int colg = n0 + wc + ni*16 + lr;
        const float bv_ = bias[(size_t)e*NO + colg];
        #pragma unroll
        for (int mi=0;mi<4;++mi){
          #pragma unroll
          for (int q=0;q<4;++q){
            float v = acc[mi][ni][q] + bv_;
            if (RELU) v = fmaxf(v, 0.f);
            st[(wrl + mi*16 + sgrp*4 + q)*136 + wc + ni*16 + lr] = f2bf(v);
          }
        }
      }
    }
    __syncthreads();
    #pragma unroll
    for (int i=0;i<4;++i){
      int idx = t + 512*i;
      int r = idx >> 4, c8 = idx & 15;
      *(uint4*)&Cb[(size_t)(row0 + h*128 + r)*NO + n0 + c8*8] = *(const uint4*)&st[r*136 + c8*8];
    }
    __syncthreads();
  }
}

// ---------------- fused tail: L2+L3+L4 per 128-row block ----------------
// Phase A: Z[128][128] = relu(H @ W2 + b2)  (K=512 staged; Zs in D4 quadrant 3)
// Phase B: D quadrants nt=0..3 = relu(Z @ W3[:,nt*128..] + b3)  (A from regs/afk)
// Phase C: out[:, ot*128..] = D @ W4 + b4  (A straight from LDS-D, B L2-hot staged)
// LDS: D4 128 KB (nt-major [4][128][128] bf16, chunk-16 swizzled) + side 16 KB.
__global__ __launch_bounds__(256, 1) void fused_tail(
    const unsigned short* H,                  // [Mpad][512]
    const unsigned short* __restrict__ W2,    // [E][128][512]
    const float* __restrict__ b2,
    const unsigned short* __restrict__ W3,    // [E][512][128]
    const float* __restrict__ b3,
    const unsigned short* __restrict__ W4,    // [E][1024][512]
    const float* __restrict__ b4,
    float* __restrict__ out,                  // [NATOMS][1024]
    const int* __restrict__ hdr,
    const int* __restrict__ perm)
{
  __shared__ __align__(16) unsigned short D4[4*128*128];  // 128 KB
  __shared__ __align__(16) unsigned short side[128*64];   // 16 KB
  unsigned short* As = side;                 // phase A: [128][64]
  unsigned short* Bs = D4;                   // phase A: [128][64] (quadrant 0 front, dead later)
  unsigned short* Zs = D4 + 3*16384;         // phase A out: [128][128] (quadrant 3)

  const int row0 = blockIdx.x * 128;
  if (row0 >= hdr[NEXP]) return;
  const int e = (row0 >= hdr[1]) + (row0 >= hdr[2]) + (row0 >= hdr[3]);

  const int t = threadIdx.x;
  const int lane = t & 63, wid = t >> 6;
  const int l8 = lane >> 3;
  const int scoff = (((lane & 7) ^ l8) << 3);
  const int lr = lane & 15, sgrp = lane >> 4;
  const int wr = (wid >> 1) * 64, wc = (wid & 1) * 64;

  f32x4 acc[4][4];
  const f32x4 z4 = {0.f,0.f,0.f,0.f};

  // ---- phase A ----
  const unsigned short* asrcA[4];
  const unsigned short* bsrcA[4];
  #pragma unroll
  for (int i=0;i<4;++i){
    asrcA[i] = H  + (size_t)(row0 + wid*32 + i*8 + l8)*512 + scoff;
    bsrcA[i] = W2 + ((size_t)e*128 + wid*32 + i*8 + l8)*512 + scoff;
  }
  #pragma unroll
  for (int mi=0;mi<4;++mi)
    #pragma unroll
    for (int ni=0;ni<4;++ni) acc[mi][ni] = z4;

  #pragma unroll 1
  for (int kt = 0; kt < 8; ++kt){
    __syncthreads();
    #pragma unroll
    for (int i=0;i<4;++i){
      glds16(asrcA[i] + kt*64, As + (wid*4+i)*512);
      glds16(bsrcA[i] + kt*64, Bs + (wid*4+i)*512);
    }
    __syncthreads();
    #pragma unroll
    for (int kk=0;kk<2;++kk){
      bf16x8 af[4], bfr[4];
      const int s = kk*4 + sgrp;
      #pragma unroll
      for (int mi=0;mi<4;++mi){
        int R = wr + mi*16 + lr;
        af[mi] = *(const bf16x8*)&As[R*64 + ((s ^ (R & 7)) << 3)];
      }
      #pragma unroll
      for (int ni=0;ni<4;++ni){
        int Cc = wc + ni*16 + lr;
        bfr[ni] = *(const bf16x8*)&Bs[Cc*64 + ((s ^ (Cc & 7)) << 3)];
      }
      #pragma unroll
      for (int mi=0;mi<4;++mi)
        #pragma unroll
        for (int ni=0;ni<4;++ni)
          acc[mi][ni] = __builtin_amdgcn_mfma_f32_16x16x32_bf16(af[mi], bfr[ni], acc[mi][ni], 0, 0, 0);
    }
  }
  __syncthreads();                      // MFMA (LDS reads) done before Zs write hits q3... (q3 untouched by A-staging; barrier orders vs glds queue too)
  // write Z -> Zs (chunk-16 swizzle)
  #pragma unroll
  for (int ni=0;ni<4;++ni){
    const int col = wc + ni*16 + lr;
    const float bv_ = b2[(size_t)e*128 + col];
    const int ch = col >> 3, cl = col & 7;
    #pragma unroll
    for (int mi=0;mi<4;++mi){
      #pragma unroll
      for (int q=0;q<4;++q){
        const int row = wr + mi*16 + sgrp*4 + q;
        float v = fmaxf(acc[mi][ni][q] + bv_, 0.f);
        Zs[row*128 + ((ch ^ (row & 15)) << 3) + cl] = f2bf(v);
      }
    }
  }
  __syncthreads();
  bf16x8 afk[4][4];
  #pragma unroll
  for (int kk=0;kk<4;++kk)
    #pragma unroll
    for (int mi=0;mi<4;++mi){
      int R = wr + mi*16 + lr;
      afk[kk][mi] = *(const bf16x8*)&Zs[R*128 + (((kk*4+sgrp) ^ (R & 15)) << 3)];
    }
  __syncthreads();                      // Zs dead; quadrants free

  // ---- phase B: D quadrants ----
  #pragma unroll 1
  for (int nt=0; nt<4; ++nt){
    #pragma unroll
    for (int mi=0;mi<4;++mi)
      #pragma unroll
      for (int ni=0;ni<4;++ni) acc[mi][ni] = z4;
    #pragma unroll
    for (int h=0; h<2; ++h){
      __syncthreads();                  // side free (prev reads done)
      #pragma unroll
      for (int i=0;i<4;++i)
        glds16(W3 + ((size_t)e*512 + nt*128 + wid*32 + i*8 + l8)*128 + h*64 + scoff,
               side + (wid*4+i)*512);
      __syncthreads();
      #pragma unroll
      for (int kk2=0;kk2<2;++kk2){
        const int sl = kk2*4 + sgrp;
        const int kk = h*2 + kk2;
        bf16x8 bfr[4];
        #pragma unroll
        for (int ni=0;ni<4;++ni){
          int Cc = wc + ni*16 + lr;
          bfr[ni] = *(const bf16x8*)&side[Cc*64 + ((sl ^ (Cc & 7)) << 3)];
        }
        #pragma unroll
        for (int mi=0;mi<4;++mi)
          #pragma unroll
          for (int ni=0;ni<4;++ni)
            acc[mi][ni] = __builtin_amdgcn_mfma_f32_16x16x32_bf16(afk[kk][mi], bfr[ni], acc[mi][ni], 0, 0, 0);
      }
    }
    // write D quadrant nt (relu + b3, chunk-16 swizzle)
    unsigned short* Dq = D4 + nt*16384;
    #pragma unroll
    for (int ni=0;ni<4;++ni){
      const int col = wc + ni*16 + lr;
      const float bv_ = b3[(size_t)e*512 + nt*128 + col];
      const int ch = col >> 3, cl = col & 7;
      #pragma unroll
      for (int mi=0;mi<4;++mi){
        #pragma unroll
        for (int q=0;q<4;++q){
          const int row = wr + mi*16 + sgrp*4 + q;
          float v = fmaxf(acc[mi][ni][q] + bv_, 0.f);
          Dq[row*128 + ((ch ^ (row & 15)) << 3) + cl] = f2bf(v);
        }
      }
    }
  }
  __syncthreads();                      // D complete (cross-wave reads next)

  // ---- phase C: out tiles ----
  #pragma unroll 1
  for (int ot=0; ot<8; ++ot){
    #pragma unroll
    for (int mi=0;mi<4;++mi)
      #pragma unroll
      for (int ni=0;ni<4;++ni) acc[mi][ni] = z4;
    #pragma unroll 1
    for (int knt=0; knt<4; ++knt){
      bf16x8 af2[4][4];
      #pragma unroll
      for (int kk=0;kk<4;++kk)
        #pragma unroll
        for (int mi=0;mi<4;++mi){
          int R = wr + mi*16 + lr;
          af2[kk][mi] = *(const bf16x8*)&D4[knt*16384 + R*128 + (((kk*4+sgrp) ^ (R & 15)) << 3)];
        }
      #pragma unroll
      for (int h=0; h<2; ++h){
        __syncthreads();
        #pragma unroll
        for (int i=0;i<4;++i)
          glds16(W4 + ((size_t)e*1024 + ot*128 + wid*32 + i*8 + l8)*512 + knt*128 + h*64 + scoff,
                 side + (wid*4+i)*512);
        __syncthreads();
        #pragma unroll
        for (int kk2=0;kk2<2;++kk2){
          const int sl = kk2*4 + sgrp;
          const int kk = h*2 + kk2;
          bf16x8 bfr[4];
          #pragma unroll
          for (int ni=0;ni<4;++ni){
            int Cc = wc + ni*16 + lr;
            bfr[ni] = *(const bf16x8*)&side[Cc*64 + ((sl ^ (Cc & 7)) << 3)];
          }
          #pragma unroll
          for (int mi=0;mi<4;++mi)
            #pragma unroll
            for (int ni=0;ni<4;++ni)
              acc[mi][ni] = __builtin_amdgcn_mfma_f32_16x16x32_bf16(af2[kk][mi], bfr[ni], acc[mi][ni], 0, 0, 0);
        }
      }
    }
    // epilogue ot: 4 row-quarters staged fp32 in side, full-line scatter rows
    float* stf = (float*)side;          // [32][128] fp32 = 16 KB
    #pragma unroll 1
    for (int q=0; q<4; ++q){
      __syncthreads();
      if ((wid >> 1) == (q >> 1)){
        #pragma unroll
        for (int m2=0;m2<2;++m2){
          const int mi = (q & 1)*2 + m2;
          #pragma unroll
          for (int ni=0;ni<4;++ni){
            const int colg = ot*128 + wc + ni*16 + lr;
            const float bv_ = b4[(size_t)e*1024 + colg];
            #pragma unroll
            for (int q4=0;q4<4;++q4){
              const int rl = m2*16 + sgrp*4 + q4;
              stf[rl*128 + wc + ni*16 + lr] = acc[mi][ni][q4] + bv_;
            }
          }
        }
      }
      __syncthreads();
      #pragma unroll
      for (int i=0;i<4;++i){
        int idx = t + 256*i;
        int r = idx >> 5, c4 = idx & 31;
        int atom = perm[row0 + q*32 + r];
        if (atom >= 0)
          *(float4*)&out[(size_t)atom*1024 + ot*128 + c4*4] = *(const float4*)&stf[r*128 + c4*4];
      }
    }
  }
}

extern "C" void kernel_launch(void* const* d_in, const int* in_sizes, int n_in,
                              void* d_out, int out_size, void* d_ws, size_t ws_size,
                              hipStream_t stream) {
  const float* X   = (const float*)d_in[0];
  const int*   sym = (const int*)  d_in[1];
  const float* We1 = (const float*)d_in[2];
  const float* be1 = (const float*)d_in[3];
  const float* We2 = (const float*)d_in[4];
  const float* be2 = (const float*)d_in[5];
  const float* Wd1 = (const float*)d_in[6];
  const float* bd1 = (const float*)d_in[7];
  const float* Wd2 = (const float*)d_in[8];
  const float* bd2 = (const float*)d_in[9];
  float* out = (float*)d_out;

  char* ws = (char*)d_ws;
  int* hdr  = (int*)(ws + WS_HDR);
  int* perm = (int*)(ws + WS_PERM);
  int* bc   = (int*)(ws + WS_BC);
  int* bb   = (int*)(ws + WS_BB);
  unsigned short* W1t = (unsigned short*)(ws + WS_W1T);
  unsigned short* W2t = (unsigned short*)(ws + WS_W2T);
  unsigned short* W3t = (unsigned short*)(ws + WS_W3T);
  unsigned short* W4t = (unsigned short*)(ws + WS_W4T);
  unsigned short* H   = (unsigned short*)(ws + WS_H);
  unsigned short* Xb  = (unsigned short*)(ws + WS_XB);

  dim3 b256(256), b512(512), b1024(1024);
  routeA<<<dim3(128), b256, 0, stream>>>(sym, bc, perm);
  routeB<<<dim3(1), dim3(64), 0, stream>>>(bc, hdr, bb);
  prep_kernel<<<dim3(SCAT + XCONV + 512 + 64 + 64 + 512), b1024, 0, stream>>>(
      sym, bb, perm, X, Xb, We1, W1t, We2, W2t, Wd1, W3t, Wd2, W4t);

  // L1: relu(Xb[perm] @ We1 + be1) -> H
  gemm_big<1024, 512, 4, true, true><<<dim3(MGRP*8*4), b512, 0, stream>>>(
      Xb, W1t, be1, H, hdr, perm);
  // L2+L3+L4 fused tail: out = relu(relu(H@We2+be2)@Wd1+bd1) @ Wd2 + bd2, scattered
  fused_tail<<<dim3(MB128), b256, 0, stream>>>(
      H, W2t, be2, W3t, bd1, W4t, bd2, out, hdr, perm);
}

// Round 19
// 206.808 us; speedup vs baseline: 3.1949x; 3.1949x over previous
//
#include <hip/hip_runtime.h>
#include <hip/hip_bf16.h>
#include <stdint.h>

typedef __bf16 bf16x8 __attribute__((ext_vector_type(8)));
typedef float  f32x4  __attribute__((ext_vector_type(4)));

#define NATOMS  32768
#define NEXP    4
#define MAXROWS (NATOMS + NEXP*256)   // 33792
#define MB256   (MAXROWS/256)         // 132
#define MB128   (MAXROWS/128)         // 264
#define MGRP    ((MB256 + 7)/8)       // 17
#define XCONV   2048                  // convert blocks: 1024 thr x 16 f32
#define SCAT    32                    // scatter blocks: 1024 thr x 1 atom

// ---------------- ws layout (bytes) ----------------
#define WS_HDR   0u
#define WS_PERM  1024u                        // int[33792] = 135168 -> ends 136192
#define WS_BC    136192u                      // int[128][4] = 2048
#define WS_BB    138240u                      // int[128][4] = 2048
#define WS_W1T   140288u                      // [4][512][1024] bf16 = 4194304
#define WS_W2T   (WS_W1T + 4194304u)
#define WS_W3T   (WS_W2T + 524288u)
#define WS_W4T   (WS_W3T + 524288u)
#define WS_H     (WS_W4T + 4194304u)          // [33792][512] bf16 = 34603008
#define WS_D     WS_H                         // alias
#define WS_XB    (WS_H + 34603008u)           // [32768][1024] bf16 = 67108864
// total ~111.3 MB

__device__ __forceinline__ unsigned short f2bf(float f){
  union { float f; uint32_t u; } v; v.f = f;
  uint32_t r = v.u + 0x7fffu + ((v.u >> 16) & 1u);   // RNE
  return (unsigned short)(r >> 16);
}
__device__ __forceinline__ uint32_t pk2(float a, float b){
  return (uint32_t)f2bf(a) | ((uint32_t)f2bf(b) << 16);
}
__device__ __forceinline__ void glds16(const void* g, void* l){
  __builtin_amdgcn_global_load_lds(
      (const __attribute__((address_space(1))) uint32_t*)g,
      (__attribute__((address_space(3))) uint32_t*)l, 16, 0, 0);
}

// ---------------- routeA: per-block histogram + perm pad-fill ----------------
__global__ __launch_bounds__(256) void routeA(const int* __restrict__ sym,
                                              int* __restrict__ bc,
                                              int* __restrict__ perm){
  __shared__ int h[NEXP];
  const int t = threadIdx.x, b = blockIdx.x;
  if (t < NEXP) h[t] = 0;
  for (int i = b*256 + t; i < MAXROWS; i += 128*256) perm[i] = -1;
  __syncthreads();
  int s = sym[b*256 + t];
  atomicAdd(&h[s], 1);
  __syncthreads();
  if (t < NEXP) bc[b*NEXP + t] = h[t];
}

// ---------------- routeB: scan block counts -> bases + hdr ----------------
__global__ __launch_bounds__(64) void routeB(const int* __restrict__ bc,
                                             int* __restrict__ hdr,
                                             int* __restrict__ bb){
  __shared__ int tot[NEXP], pof[NEXP+1];
  const int t = threadIdx.x;
  if (t < NEXP){
    int s = 0;
    for (int i=0;i<128;++i) s += bc[i*NEXP + t];
    tot[t] = s;
  }
  __syncthreads();
  if (t == 0){
    int o = 0; pof[0] = 0;
    for (int e=0;e<NEXP;++e){ o += (tot[e]+255)&~255; pof[e+1]=o; }
    for (int e=0;e<=NEXP;++e) hdr[e]=pof[e];
  }
  __syncthreads();
  if (t < NEXP){
    int run = pof[t];
    for (int i=0;i<128;++i){ bb[i*NEXP + t] = run; run += bc[i*NEXP + t]; }
  }
}

// ---------------- weight transpose helper (1024 threads) ----------------
template<int K, int NO>
__device__ __forceinline__ void wtile1024(const float* __restrict__ W,
                                          unsigned short* __restrict__ Bt,
                                          int b, unsigned short (*tile)[65]){
  const int nx = NO/64, ny = K/64;
  const int e = b / (nx*ny), rem = b % (nx*ny);
  const int k0 = (rem / nx) * 64;
  const int n0 = (rem % nx) * 64;
  const int t  = threadIdx.x;
  const int c  = t & 63;
  const float* Wb = W + ((size_t)e*K + k0)*NO + n0;
  #pragma unroll
  for (int i=0;i<4;++i){
    int r = (t>>6) + i*16;
    tile[r][c] = f2bf(Wb[(size_t)r*NO + c]);
  }
  __syncthreads();
  unsigned short* Bb = Bt + ((size_t)e*NO + n0)*K + k0;
  #pragma unroll
  for (int i=0;i<4;++i){
    int r = (t>>6) + i*16;
    Bb[(size_t)r*K + c] = tile[c][r];
  }
}

// ---------------- prep: scatter + X convert (NT loads) + weight transposes ----------------
__global__ __launch_bounds__(1024) void prep_kernel(
    const int*   __restrict__ sym,  const int* __restrict__ bb,  int* __restrict__ perm,
    const float* __restrict__ X,    unsigned short* __restrict__ Xb,
    const float* __restrict__ We1, unsigned short* __restrict__ W1t,
    const float* __restrict__ We2, unsigned short* __restrict__ W2t,
    const float* __restrict__ Wd1, unsigned short* __restrict__ W3t,
    const float* __restrict__ Wd2, unsigned short* __restrict__ W4t)
{
  __shared__ unsigned short tile[64][65];
  __shared__ int wc[16][NEXP];

  int b = blockIdx.x;
  const int t = threadIdx.x;

  if (b < SCAT){
    // ---- stable parallel scatter: 1 atom/thread ----
    const int lane = t & 63, w = t >> 6;
    const int a = b*1024 + t;
    const int s = sym[a];
    unsigned long long b0 = __ballot(s & 1);
    unsigned long long b1 = __ballot(s & 2);
    unsigned long long meq = ((s & 1) ? b0 : ~b0) & ((s & 2) ? b1 : ~b1);
    unsigned long long lt  = ((unsigned long long)1 << lane) - 1;
    const int lofs = __popcll(meq & lt);
    if (lane == 0){
      unsigned long long m00 = ~b0 & ~b1, m01 = b0 & ~b1, m10 = ~b0 & b1, m11 = b0 & b1;
      wc[w][0] = __popcll(m00); wc[w][1] = __popcll(m01);
      wc[w][2] = __popcll(m10); wc[w][3] = __popcll(m11);
    }
    __syncthreads();
    const int rb = (t >> 8);          // which 256-atom sub-block (0..3)
    int wbase_rb = 0;
    for (int i = rb*4; i < w; ++i) wbase_rb += wc[i][s];
    const int slot = bb[(b*4 + rb)*NEXP + s] + wbase_rb + lofs;
    perm[slot] = a;
    return;
  }
  b -= SCAT;
  if (b < XCONV){
    // ---- linear X convert: 16 floats/thread, non-temporal reads (X read once) ----
    size_t i = ((size_t)b*1024 + t) * 16;
    const f32x4* src = (const f32x4*)(X + i);
    f32x4 f0 = __builtin_nontemporal_load(src);
    f32x4 f1 = __builtin_nontemporal_load(src + 1);
    f32x4 f2 = __builtin_nontemporal_load(src + 2);
    f32x4 f3 = __builtin_nontemporal_load(src + 3);
    uint4 o0, o1;
    o0.x = pk2(f0[0],f0[1]); o0.y = pk2(f0[2],f0[3]);
    o0.z = pk2(f1[0],f1[1]); o0.w = pk2(f1[2],f1[3]);
    o1.x = pk2(f2[0],f2[1]); o1.y = pk2(f2[2],f2[3]);
    o1.z = pk2(f3[0],f3[1]); o1.w = pk2(f3[2],f3[3]);
    *(uint4*)&Xb[i]     = o0;
    *(uint4*)&Xb[i + 8] = o1;
    return;
  }
  b -= XCONV;
  if (b < 512){ wtile1024<1024, 512>(We1, W1t, b, tile); return; }
  b -= 512;
  if (b <  64){ wtile1024< 512, 128>(We2, W2t, b, tile); return; }
  b -= 64;
  if (b <  64){ wtile1024< 128, 512>(Wd1, W3t, b, tile); return; }
  b -= 64;
  wtile1024< 512,1024>(Wd2, W4t, b, tile);
}

// ---------------- 256x128 tile MFMA GEMM, 8 waves (4x2), BK=64 (R6-proven) ----------------
template<int K, int NO, int NT, bool RELU, bool GATHER, bool FINAL>
__global__ __launch_bounds__(512, 4) void gemm_big(
    const unsigned short* __restrict__ A,
    const unsigned short* __restrict__ Bt,
    const float* __restrict__ bias,
    unsigned short* __restrict__ Cb,
    float* __restrict__ Cf,
    const int* __restrict__ hdr,
    const int* __restrict__ perm)
{
  __shared__ __align__(16) unsigned short smem[256*64 + 128*64];  // 48 KB
  __shared__ int sperm[256];
  unsigned short* As = smem;             // [256][64] linear, source-swizzled
  unsigned short* Bs = smem + 256*64;    // [128][64]

  const int b = blockIdx.x;
  const int grp = b / (8*NT), rem = b % (8*NT);
  const int rowblk = grp*8 + (rem & 7);
  const int row0 = rowblk * 256;
  if (row0 >= hdr[NEXP]) return;
  const int ntile = rem >> 3;
  const int e = (row0 >= hdr[1]) + (row0 >= hdr[2]) + (row0 >= hdr[3]);
  const int n0 = ntile * 128;

  const int t = threadIdx.x;
  const int lane = t & 63, wid = t >> 6;

  if constexpr (GATHER || FINAL){
    if (t < 256) sperm[t] = perm[row0 + t];
    __syncthreads();
  }

  const int l8 = lane >> 3;
  const int scoff = (((lane & 7) ^ l8) << 3);   // swizzled source chunk (shorts)

  const unsigned short* asrc[4];
  #pragma unroll
  for (int i=0;i<4;++i){
    const int r = wid*32 + i*8 + l8;
    long grow;
    if constexpr (GATHER){
      int a = sperm[r];
      grow = (a < 0) ? 0 : a;                   // pad rows: junk, dropped at FINAL
    } else {
      grow = row0 + r;
    }
    asrc[i] = A + (size_t)grow*K + scoff;
  }
  const unsigned short* bsrc[2];
  #pragma unroll
  for (int i=0;i<2;++i)
    bsrc[i] = Bt + ((size_t)e*NO + n0 + wid*16 + i*8 + l8)*K + scoff;

  const int lr   = lane & 15;
  const int sgrp = lane >> 4;
  const int wr   = (wid >> 1) * 64;   // 0,64,128,192
  const int wc   = (wid & 1) * 64;    // 0,64

  f32x4 acc[4][4];
  const f32x4 z4 = {0.f,0.f,0.f,0.f};
  #pragma unroll
  for (int mi=0;mi<4;++mi)
    #pragma unroll
    for (int ni=0;ni<4;++ni) acc[mi][ni] = z4;

  #pragma unroll 1
  for (int kt = 0; kt < K/64; ++kt){
    __syncthreads();                    // previous MFMA done with As/Bs
    #pragma unroll
    for (int i=0;i<4;++i)
      glds16(asrc[i] + kt*64, As + (wid*4+i)*512);
    #pragma unroll
    for (int i=0;i<2;++i)
      glds16(bsrc[i] + kt*64, Bs + (wid*2+i)*512);
    __syncthreads();                    // drains vmcnt

    #pragma unroll
    for (int kk=0;kk<2;++kk){
      bf16x8 af[4], bfr[4];
      const int s = kk*4 + sgrp;
      #pragma unroll
      for (int mi=0;mi<4;++mi){
        int R = wr + mi*16 + lr;
        af[mi] = *(const bf16x8*)&As[R*64 + ((s ^ (R & 7)) << 3)];
      }
      #pragma unroll
      for (int ni=0;ni<4;++ni){
        int Cc = wc + ni*16 + lr;
        bfr[ni] = *(const bf16x8*)&Bs[Cc*64 + ((s ^ (Cc & 7)) << 3)];
      }
      #pragma unroll
      for (int mi=0;mi<4;++mi)
        #pragma unroll
        for (int ni=0;ni<4;++ni)
          acc[mi][ni] = __builtin_amdgcn_mfma_f32_16x16x32_bf16(af[mi], bfr[ni], acc[mi][ni], 0, 0, 0);
    }
  }

  // ---------- epilogue: LDS-staged, full-line row writes ----------
  __syncthreads();                      // done with As/Bs
  if constexpr (FINAL){
    float* stf = (float*)smem;          // [64][132] fp32
    #pragma unroll
    for (int qr=0; qr<4; ++qr){
      if ((wid >> 1) == qr){
        #pragma unroll
        for (int ni=0;ni<4;++ni){
          const int colg = n0 + wc + ni*16 + lr;
          const float bv_ = bias[(size_t)e*NO + colg];
          #pragma unroll
          for (int mi=0;mi<4;++mi){
            #pragma unroll
            for (int q=0;q<4;++q){
              float v = acc[mi][ni][q] + bv_;
              if (RELU) v = fmaxf(v, 0.f);
              stf[(mi*16 + sgrp*4 + q)*132 + wc + ni*16 + lr] = v;
            }
          }
        }
      }
      __syncthreads();
      #pragma unroll
      for (int i=0;i<4;++i){
        int idx = t + 512*i;
        int r = idx >> 5, c4 = idx & 31;
        int atom = sperm[qr*64 + r];
        if (atom >= 0){
          f32x4 v = *(const f32x4*)&stf[r*132 + c4*4];
          __builtin_nontemporal_store(v, (f32x4*)&Cf[(size_t)atom*NO + n0 + c4*4]);
        }
      }
      __syncthreads();
    }
  } else {
    unsigned short* st = smem;          // [128][136] bf16
    const int wrl = ((wid >> 1) & 1) * 64;
    #pragma unroll
    for (int h=0; h<2; ++h){
      if ((wid >> 2) == h){
        #pragma unroll
        for (int ni=0;ni<4;++ni){
          const int colg = n0 + wc + ni*16 + lr;
          const float bv_ = bias[(size_t)e*NO + colg];
          #pragma unroll
          for (int mi=0;mi<4;++mi){
            #pragma unroll
            for (int q=0;q<4;++q){
              float v = acc[mi][ni][q] + bv_;
              if (RELU) v = fmaxf(v, 0.f);
              st[(wrl + mi*16 + sgrp*4 + q)*136 + wc + ni*16 + lr] = f2bf(v);
            }
          }
        }
      }
      __syncthreads();
      #pragma unroll
      for (int i=0;i<4;++i){
        int idx = t + 512*i;
        int r = idx >> 4, c8 = idx & 15;
        *(uint4*)&Cb[(size_t)(row0 + h*128 + r)*NO + n0 + c8*8] = *(const uint4*)&st[r*136 + c8*8];
      }
      __syncthreads();
    }
  }
}

// ---------------- fused L2+L3: Z kept in LDS, 128-row blocks, 4 waves ----------------
__global__ __launch_bounds__(256, 2) void fused_mid(
    const unsigned short* H,
    const unsigned short* __restrict__ W2,
    const float* __restrict__ b2,
    const unsigned short* __restrict__ W3,
    const float* __restrict__ b3,
    unsigned short* D,
    const int* __restrict__ hdr)
{
  __shared__ __align__(16) unsigned short un[128*136];
  __shared__ __align__(16) unsigned short Zs[128*128];
  unsigned short* As = un;
  unsigned short* Bs = un + 128*64;

  const int row0 = blockIdx.x * 128;
  if (row0 >= hdr[NEXP]) return;
  const int e = (row0 >= hdr[1]) + (row0 >= hdr[2]) + (row0 >= hdr[3]);

  const int t = threadIdx.x;
  const int lane = t & 63, wid = t >> 6;
  const int l8 = lane >> 3;
  const int scoff = (((lane & 7) ^ l8) << 3);
  const int lr = lane & 15, sgrp = lane >> 4;
  const int wr = (wid >> 1) * 64, wc = (wid & 1) * 64;

  const unsigned short* asrc[4];
  const unsigned short* bsrc[4];
  #pragma unroll
  for (int i=0;i<4;++i){
    asrc[i] = H  + (size_t)(row0 + wid*32 + i*8 + l8)*512 + scoff;
    bsrc[i] = W2 + ((size_t)e*128 + wid*32 + i*8 + l8)*512 + scoff;
  }

  f32x4 acc[4][4];
  const f32x4 z4 = {0.f,0.f,0.f,0.f};
  #pragma unroll
  for (int mi=0;mi<4;++mi)
    #pragma unroll
    for (int ni=0;ni<4;++ni) acc[mi][ni] = z4;

  #pragma unroll 1
  for (int kt = 0; kt < 8; ++kt){
    __syncthreads();
    #pragma unroll
    for (int i=0;i<4;++i){
      glds16(asrc[i] + kt*64, As + (wid*4+i)*512);
      glds16(bsrc[i] + kt*64, Bs + (wid*4+i)*512);
    }
    __syncthreads();
    #pragma unroll
    for (int kk=0;kk<2;++kk){
      bf16x8 af[4], bfr[4];
      const int s = kk*4 + sgrp;
      #pragma unroll
      for (int mi=0;mi<4;++mi){
        int R = wr + mi*16 + lr;
        af[mi] = *(const bf16x8*)&As[R*64 + ((s ^ (R & 7)) << 3)];
      }
      #pragma unroll
      for (int ni=0;ni<4;++ni){
        int Cc = wc + ni*16 + lr;
        bfr[ni] = *(const bf16x8*)&Bs[Cc*64 + ((s ^ (Cc & 7)) << 3)];
      }
      #pragma unroll
      for (int mi=0;mi<4;++mi)
        #pragma unroll
        for (int ni=0;ni<4;++ni)
          acc[mi][ni] = __builtin_amdgcn_mfma_f32_16x16x32_bf16(af[mi], bfr[ni], acc[mi][ni], 0, 0, 0);
    }
  }
  #pragma unroll
  for (int ni=0;ni<4;++ni){
    const int col = wc + ni*16 + lr;
    const float bv_ = b2[(size_t)e*128 + col];
    const int ch = col >> 3, cl = col & 7;
    #pragma unroll
    for (int mi=0;mi<4;++mi){
      #pragma unroll
      for (int q=0;q<4;++q){
        const int row = wr + mi*16 + sgrp*4 + q;
        float v = fmaxf(acc[mi][ni][q] + bv_, 0.f);
        Zs[row*128 + ((ch ^ (row & 15)) << 3) + cl] = f2bf(v);
      }
    }
  }
  __syncthreads();

  bf16x8 afk[4][4];
  #pragma unroll
  for (int kk=0;kk<4;++kk)
    #pragma unroll
    for (int mi=0;mi<4;++mi){
      int R = wr + mi*16 + lr;
      afk[kk][mi] = *(const bf16x8*)&Zs[R*128 + (((kk*4+sgrp) ^ (R & 15)) << 3)];
    }

  #pragma unroll 1
  for (int nt=0; nt<4; ++nt){
    #pragma unroll
    for (int i=0;i<8;++i){
      int R = (wid*8 + i)*4 + (lane >> 4);
      int sch = (lane & 15) ^ (R & 15);
      glds16(W3 + ((size_t)e*512 + nt*128 + R)*128 + sch*8, un + (size_t)(wid*8+i)*512);
    }
    __syncthreads();

    #pragma unroll
    for (int mi=0;mi<4;++mi)
      #pragma unroll
      for (int ni=0;ni<4;++ni) acc[mi][ni] = z4;

    #pragma unroll
    for (int kk=0;kk<4;++kk){
      bf16x8 bfr[4];
      const int s = kk*4 + sgrp;
      #pragma unroll
      for (int ni=0;ni<4;++ni){
        int Cc = wc + ni*16 + lr;
        bfr[ni] = *(const bf16x8*)&un[Cc*128 + ((s ^ (Cc & 15)) << 3)];
      }
      #pragma unroll
      for (int mi=0;mi<4;++mi)
        #pragma unroll
        for (int ni=0;ni<4;++ni)
          acc[mi][ni] = __builtin_amdgcn_mfma_f32_16x16x32_bf16(afk[kk][mi], bfr[ni], acc[mi][ni], 0, 0, 0);
    }
    __syncthreads();

    #pragma unroll
    for (int ni=0;ni<4;++ni){
      const int col = wc + ni*16 + lr;
      const float bv_ = b3[(size_t)e*512 + nt*128 + col];
      #pragma unroll
      for (int mi=0;mi<4;++mi){
        #pragma unroll
        for (int q=0;q<4;++q){
          const int row = wr + mi*16 + sgrp*4 + q;
          float v = fmaxf(acc[mi][ni][q] + bv_, 0.f);
          un[row*136 + col] = f2bf(v);
        }
      }
    }
    __syncthreads();
    #pragma unroll
    for (int i=0;i<8;++i){
      int idx = t + 256*i;
      int r = idx >> 4, c8 = idx & 15;
      *(uint4*)&D[(size_t)(row0 + r)*512 + nt*128 + c8*8] = *(const uint4*)&un[r*136 + c8*8];
    }
    __syncthreads();
  }
}

extern "C" void kernel_launch(void* const* d_in, const int* in_sizes, int n_in,
                              void* d_out, int out_size, void* d_ws, size_t ws_size,
                              hipStream_t stream) {
  const float* X   = (const float*)d_in[0];
  const int*   sym = (const int*)  d_in[1];
  const float* We1 = (const float*)d_in[2];
  const float* be1 = (const float*)d_in[3];
  const float* We2 = (const float*)d_in[4];
  const float* be2 = (const float*)d_in[5];
  const float* Wd1 = (const float*)d_in[6];
  const float* bd1 = (const float*)d_in[7];
  const float* Wd2 = (const float*)d_in[8];
  const float* bd2 = (const float*)d_in[9];
  float* out = (float*)d_out;

  char* ws = (char*)d_ws;
  int* hdr  = (int*)(ws + WS_HDR);
  int* perm = (int*)(ws + WS_PERM);
  int* bc   = (int*)(ws + WS_BC);
  int* bb   = (int*)(ws + WS_BB);
  unsigned short* W1t = (unsigned short*)(ws + WS_W1T);
  unsigned short* W2t = (unsigned short*)(ws + WS_W2T);
  unsigned short* W3t = (unsigned short*)(ws + WS_W3T);
  unsigned short* W4t = (unsigned short*)(ws + WS_W4T);
  unsigned short* H   = (unsigned short*)(ws + WS_H);
  unsigned short* Dd  = (unsigned short*)(ws + WS_D);   // aliases H
  unsigned short* Xb  = (unsigned short*)(ws + WS_XB);

  dim3 b256(256), b512(512), b1024(1024);
  routeA<<<dim3(128), b256, 0, stream>>>(sym, bc, perm);
  routeB<<<dim3(1), dim3(64), 0, stream>>>(bc, hdr, bb);
  // merged: scatter (32 blocks) || X convert || weight transposes
  prep_kernel<<<dim3(SCAT + XCONV + 512 + 64 + 64 + 512), b1024, 0, stream>>>(
      sym, bb, perm, X, Xb, We1, W1t, We2, W2t, Wd1, W3t, Wd2, W4t);

  // L1: relu(Xb[perm] @ We1 + be1) -> H   (gathered glds, 256x128, 8 waves)
  gemm_big<1024, 512, 4, true,  true,  false><<<dim3(MGRP*8*4), b512, 0, stream>>>(
      Xb, W1t, be1, H, nullptr, hdr, perm);
  // L2+L3 fused
  fused_mid<<<dim3(MB128), b256, 0, stream>>>(H, W2t, be2, W3t, bd1, Dd, hdr);
  // L4: scatter fp32 rows to out via perm (non-temporal final stores)
  gemm_big< 512,1024, 8, false, false, true ><<<dim3(MGRP*8*8), b512, 0, stream>>>(
      Dd, W4t, bd2, nullptr, out, hdr, perm);
}

// Round 20
// 196.765 us; speedup vs baseline: 3.3580x; 1.0510x over previous
//
#include <hip/hip_runtime.h>
#include <hip/hip_bf16.h>
#include <stdint.h>

typedef __bf16 bf16x8 __attribute__((ext_vector_type(8)));
typedef float  f32x4  __attribute__((ext_vector_type(4)));

#define NATOMS  32768
#define NEXP    4
#define MAXROWS (NATOMS + NEXP*256)   // 33792
#define MB256   (MAXROWS/256)         // 132
#define MB128   (MAXROWS/128)         // 264
#define MGRP    ((MB256 + 7)/8)       // 17
#define XCONV   2048                  // convert blocks: 1024 thr x 16 f32
#define SCAT    32                    // scatter blocks: 1024 thr x 1 atom

// ---------------- ws layout (bytes) ----------------
#define WS_HDR   0u
#define WS_PERM  1024u                        // int[33792] = 135168 -> ends 136192
#define WS_BC    136192u                      // int[128][4] = 2048
#define WS_BB    138240u                      // int[128][4] = 2048
#define WS_W1T   140288u                      // [4][512][1024] bf16 = 4194304
#define WS_W2T   (WS_W1T + 4194304u)
#define WS_W3T   (WS_W2T + 524288u)
#define WS_W4T   (WS_W3T + 524288u)
#define WS_H     (WS_W4T + 4194304u)          // [33792][512] bf16 = 34603008
#define WS_D     WS_H                         // alias
#define WS_XB    (WS_H + 34603008u)           // [32768][1024] bf16 = 67108864
// total ~111.3 MB

__device__ __forceinline__ unsigned short f2bf(float f){
  union { float f; uint32_t u; } v; v.f = f;
  uint32_t r = v.u + 0x7fffu + ((v.u >> 16) & 1u);   // RNE
  return (unsigned short)(r >> 16);
}
__device__ __forceinline__ uint32_t pk2(float a, float b){
  return (uint32_t)f2bf(a) | ((uint32_t)f2bf(b) << 16);
}
__device__ __forceinline__ void glds16(const void* g, void* l){
  __builtin_amdgcn_global_load_lds(
      (const __attribute__((address_space(1))) uint32_t*)g,
      (__attribute__((address_space(3))) uint32_t*)l, 16, 0, 0);
}

// ---------------- routeA: per-block histogram + perm pad-fill ----------------
__global__ __launch_bounds__(256) void routeA(const int* __restrict__ sym,
                                              int* __restrict__ bc,
                                              int* __restrict__ perm){
  __shared__ int h[NEXP];
  const int t = threadIdx.x, b = blockIdx.x;
  if (t < NEXP) h[t] = 0;
  for (int i = b*256 + t; i < MAXROWS; i += 128*256) perm[i] = -1;
  __syncthreads();
  int s = sym[b*256 + t];
  atomicAdd(&h[s], 1);
  __syncthreads();
  if (t < NEXP) bc[b*NEXP + t] = h[t];
}

// ---------------- routeB: scan block counts -> bases + hdr ----------------
__global__ __launch_bounds__(64) void routeB(const int* __restrict__ bc,
                                             int* __restrict__ hdr,
                                             int* __restrict__ bb){
  __shared__ int tot[NEXP], pof[NEXP+1];
  const int t = threadIdx.x;
  if (t < NEXP){
    int s = 0;
    for (int i=0;i<128;++i) s += bc[i*NEXP + t];
    tot[t] = s;
  }
  __syncthreads();
  if (t == 0){
    int o = 0; pof[0] = 0;
    for (int e=0;e<NEXP;++e){ o += (tot[e]+255)&~255; pof[e+1]=o; }
    for (int e=0;e<=NEXP;++e) hdr[e]=pof[e];
  }
  __syncthreads();
  if (t < NEXP){
    int run = pof[t];
    for (int i=0;i<128;++i){ bb[i*NEXP + t] = run; run += bc[i*NEXP + t]; }
  }
}

// ---------------- weight transpose helper (1024 threads) ----------------
template<int K, int NO>
__device__ __forceinline__ void wtile1024(const float* __restrict__ W,
                                          unsigned short* __restrict__ Bt,
                                          int b, unsigned short (*tile)[65]){
  const int nx = NO/64, ny = K/64;
  const int e = b / (nx*ny), rem = b % (nx*ny);
  const int k0 = (rem / nx) * 64;
  const int n0 = (rem % nx) * 64;
  const int t  = threadIdx.x;
  const int c  = t & 63;
  const float* Wb = W + ((size_t)e*K + k0)*NO + n0;
  #pragma unroll
  for (int i=0;i<4;++i){
    int r = (t>>6) + i*16;
    tile[r][c] = f2bf(Wb[(size_t)r*NO + c]);
  }
  __syncthreads();
  unsigned short* Bb = Bt + ((size_t)e*NO + n0)*K + k0;
  #pragma unroll
  for (int i=0;i<4;++i){
    int r = (t>>6) + i*16;
    Bb[(size_t)r*K + c] = tile[c][r];
  }
}

// ---------------- prep: scatter blocks + X convert + weight transposes ----------------
__global__ __launch_bounds__(1024) void prep_kernel(
    const int*   __restrict__ sym,  const int* __restrict__ bb,  int* __restrict__ perm,
    const float* __restrict__ X,    unsigned short* __restrict__ Xb,
    const float* __restrict__ We1, unsigned short* __restrict__ W1t,
    const float* __restrict__ We2, unsigned short* __restrict__ W2t,
    const float* __restrict__ Wd1, unsigned short* __restrict__ W3t,
    const float* __restrict__ Wd2, unsigned short* __restrict__ W4t)
{
  __shared__ unsigned short tile[64][65];
  __shared__ int wc[16][NEXP];

  int b = blockIdx.x;
  const int t = threadIdx.x;

  if (b < SCAT){
    // ---- stable parallel scatter: 1 atom/thread ----
    const int lane = t & 63, w = t >> 6;
    const int a = b*1024 + t;
    const int s = sym[a];
    unsigned long long b0 = __ballot(s & 1);
    unsigned long long b1 = __ballot(s & 2);
    unsigned long long meq = ((s & 1) ? b0 : ~b0) & ((s & 2) ? b1 : ~b1);
    unsigned long long lt  = ((unsigned long long)1 << lane) - 1;
    const int lofs = __popcll(meq & lt);
    if (lane == 0){
      unsigned long long m00 = ~b0 & ~b1, m01 = b0 & ~b1, m10 = ~b0 & b1, m11 = b0 & b1;
      wc[w][0] = __popcll(m00); wc[w][1] = __popcll(m01);
      wc[w][2] = __popcll(m10); wc[w][3] = __popcll(m11);
    }
    __syncthreads();
    const int rb = (t >> 8);          // which 256-atom sub-block (0..3)
    int wbase_rb = 0;
    for (int i = rb*4; i < w; ++i) wbase_rb += wc[i][s];
    const int slot = bb[(b*4 + rb)*NEXP + s] + wbase_rb + lofs;
    perm[slot] = a;
    return;
  }
  b -= SCAT;
  if (b < XCONV){
    // ---- linear X convert: 16 floats/thread (R12-identical) ----
    size_t i = ((size_t)b*1024 + t) * 16;
    const float4* src = (const float4*)(X + i);
    float4 f0 = src[0], f1 = src[1], f2 = src[2], f3 = src[3];
    uint4 o0, o1;
    o0.x = pk2(f0.x,f0.y); o0.y = pk2(f0.z,f0.w);
    o0.z = pk2(f1.x,f1.y); o0.w = pk2(f1.z,f1.w);
    o1.x = pk2(f2.x,f2.y); o1.y = pk2(f2.z,f2.w);
    o1.z = pk2(f3.x,f3.y); o1.w = pk2(f3.z,f3.w);
    *(uint4*)&Xb[i]     = o0;
    *(uint4*)&Xb[i + 8] = o1;
    return;
  }
  b -= XCONV;
  if (b < 512){ wtile1024<1024, 512>(We1, W1t, b, tile); return; }
  b -= 512;
  if (b <  64){ wtile1024< 512, 128>(We2, W2t, b, tile); return; }
  b -= 64;
  if (b <  64){ wtile1024< 128, 512>(Wd1, W3t, b, tile); return; }
  b -= 64;
  wtile1024< 512,1024>(Wd2, W4t, b, tile);
}

// ---------------- 256x128 tile MFMA GEMM, 8 waves (4x2), BK=64 (R6-proven) ----------------
template<int K, int NO, int NT, bool RELU, bool GATHER, bool FINAL>
__global__ __launch_bounds__(512, 4) void gemm_big(
    const unsigned short* __restrict__ A,
    const unsigned short* __restrict__ Bt,
    const float* __restrict__ bias,
    unsigned short* __restrict__ Cb,
    float* __restrict__ Cf,
    const int* __restrict__ hdr,
    const int* __restrict__ perm)
{
  __shared__ __align__(16) unsigned short smem[256*64 + 128*64];  // 48 KB
  __shared__ int sperm[256];
  unsigned short* As = smem;             // [256][64] linear, source-swizzled
  unsigned short* Bs = smem + 256*64;    // [128][64]

  const int b = blockIdx.x;
  const int grp = b / (8*NT), rem = b % (8*NT);
  const int rowblk = grp*8 + (rem & 7);
  const int row0 = rowblk * 256;
  if (row0 >= hdr[NEXP]) return;
  const int ntile = rem >> 3;
  const int e = (row0 >= hdr[1]) + (row0 >= hdr[2]) + (row0 >= hdr[3]);
  const int n0 = ntile * 128;

  const int t = threadIdx.x;
  const int lane = t & 63, wid = t >> 6;

  if constexpr (GATHER || FINAL){
    if (t < 256) sperm[t] = perm[row0 + t];
    __syncthreads();
  }

  const int l8 = lane >> 3;
  const int scoff = (((lane & 7) ^ l8) << 3);   // swizzled source chunk (shorts)

  const unsigned short* asrc[4];
  #pragma unroll
  for (int i=0;i<4;++i){
    const int r = wid*32 + i*8 + l8;
    long grow;
    if constexpr (GATHER){
      int a = sperm[r];
      grow = (a < 0) ? 0 : a;                   // pad rows: junk, dropped at FINAL
    } else {
      grow = row0 + r;
    }
    asrc[i] = A + (size_t)grow*K + scoff;
  }
  const unsigned short* bsrc[2];
  #pragma unroll
  for (int i=0;i<2;++i)
    bsrc[i] = Bt + ((size_t)e*NO + n0 + wid*16 + i*8 + l8)*K + scoff;

  const int lr   = lane & 15;
  const int sgrp = lane >> 4;
  const int wr   = (wid >> 1) * 64;   // 0,64,128,192
  const int wc   = (wid & 1) * 64;    // 0,64

  f32x4 acc[4][4];
  const f32x4 z4 = {0.f,0.f,0.f,0.f};
  #pragma unroll
  for (int mi=0;mi<4;++mi)
    #pragma unroll
    for (int ni=0;ni<4;++ni) acc[mi][ni] = z4;

  #pragma unroll 1
  for (int kt = 0; kt < K/64; ++kt){
    __syncthreads();                    // previous MFMA done with As/Bs
    #pragma unroll
    for (int i=0;i<4;++i)
      glds16(asrc[i] + kt*64, As + (wid*4+i)*512);
    #pragma unroll
    for (int i=0;i<2;++i)
      glds16(bsrc[i] + kt*64, Bs + (wid*2+i)*512);
    __syncthreads();                    // drains vmcnt

    #pragma unroll
    for (int kk=0;kk<2;++kk){
      bf16x8 af[4], bfr[4];
      const int s = kk*4 + sgrp;
      #pragma unroll
      for (int mi=0;mi<4;++mi){
        int R = wr + mi*16 + lr;
        af[mi] = *(const bf16x8*)&As[R*64 + ((s ^ (R & 7)) << 3)];
      }
      #pragma unroll
      for (int ni=0;ni<4;++ni){
        int Cc = wc + ni*16 + lr;
        bfr[ni] = *(const bf16x8*)&Bs[Cc*64 + ((s ^ (Cc & 7)) << 3)];
      }
      #pragma unroll
      for (int mi=0;mi<4;++mi)
        #pragma unroll
        for (int ni=0;ni<4;++ni)
          acc[mi][ni] = __builtin_amdgcn_mfma_f32_16x16x32_bf16(af[mi], bfr[ni], acc[mi][ni], 0, 0, 0);
    }
  }

  // ---------- epilogue: LDS-staged, full-line row writes ----------
  __syncthreads();                      // done with As/Bs
  if constexpr (FINAL){
    float* stf = (float*)smem;          // [64][132] fp32
    #pragma unroll
    for (int qr=0; qr<4; ++qr){
      if ((wid >> 1) == qr){
        #pragma unroll
        for (int ni=0;ni<4;++ni){
          const int colg = n0 + wc + ni*16 + lr;
          const float bv_ = bias[(size_t)e*NO + colg];
          #pragma unroll
          for (int mi=0;mi<4;++mi){
            #pragma unroll
            for (int q=0;q<4;++q){
              float v = acc[mi][ni][q] + bv_;
              if (RELU) v = fmaxf(v, 0.f);
              stf[(mi*16 + sgrp*4 + q)*132 + wc + ni*16 + lr] = v;
            }
          }
        }
      }
      __syncthreads();
      #pragma unroll
      for (int i=0;i<4;++i){
        int idx = t + 512*i;
        int r = idx >> 5, c4 = idx & 31;
        int atom = sperm[qr*64 + r];
        if (atom >= 0)
          *(float4*)&Cf[(size_t)atom*NO + n0 + c4*4] = *(const float4*)&stf[r*132 + c4*4];
      }
      __syncthreads();
    }
  } else {
    unsigned short* st = smem;          // [128][136] bf16
    const int wrl = ((wid >> 1) & 1) * 64;
    #pragma unroll
    for (int h=0; h<2; ++h){
      if ((wid >> 2) == h){
        #pragma unroll
        for (int ni=0;ni<4;++ni){
          const int colg = n0 + wc + ni*16 + lr;
          const float bv_ = bias[(size_t)e*NO + colg];
          #pragma unroll
          for (int mi=0;mi<4;++mi){
            #pragma unroll
            for (int q=0;q<4;++q){
              float v = acc[mi][ni][q] + bv_;
              if (RELU) v = fmaxf(v, 0.f);
              st[(wrl + mi*16 + sgrp*4 + q)*136 + wc + ni*16 + lr] = f2bf(v);
            }
          }
        }
      }
      __syncthreads();
      #pragma unroll
      for (int i=0;i<4;++i){
        int idx = t + 512*i;
        int r = idx >> 4, c8 = idx & 15;
        *(uint4*)&Cb[(size_t)(row0 + h*128 + r)*NO + n0 + c8*8] = *(const uint4*)&st[r*136 + c8*8];
      }
      __syncthreads();
    }
  }
}

// ---------------- fused L2+L3: Z kept in LDS, 128-row blocks, 4 waves ----------------
__global__ __launch_bounds__(256, 2) void fused_mid(
    const unsigned short* H,
    const unsigned short* __restrict__ W2,
    const float* __restrict__ b2,
    const unsigned short* __restrict__ W3,
    const float* __restrict__ b3,
    unsigned short* D,
    const int* __restrict__ hdr)
{
  __shared__ __align__(16) unsigned short un[128*136];
  __shared__ __align__(16) unsigned short Zs[128*128];
  unsigned short* As = un;
  unsigned short* Bs = un + 128*64;

  const int row0 = blockIdx.x * 128;
  if (row0 >= hdr[NEXP]) return;
  const int e = (row0 >= hdr[1]) + (row0 >= hdr[2]) + (row0 >= hdr[3]);

  const int t = threadIdx.x;
  const int lane = t & 63, wid = t >> 6;
  const int l8 = lane >> 3;
  const int scoff = (((lane & 7) ^ l8) << 3);
  const int lr = lane & 15, sgrp = lane >> 4;
  const int wr = (wid >> 1) * 64, wc = (wid & 1) * 64;

  const unsigned short* asrc[4];
  const unsigned short* bsrc[4];
  #pragma unroll
  for (int i=0;i<4;++i){
    asrc[i] = H  + (size_t)(row0 + wid*32 + i*8 + l8)*512 + scoff;
    bsrc[i] = W2 + ((size_t)e*128 + wid*32 + i*8 + l8)*512 + scoff;
  }

  f32x4 acc[4][4];
  const f32x4 z4 = {0.f,0.f,0.f,0.f};
  #pragma unroll
  for (int mi=0;mi<4;++mi)
    #pragma unroll
    for (int ni=0;ni<4;++ni) acc[mi][ni] = z4;

  #pragma unroll 1
  for (int kt = 0; kt < 8; ++kt){
    __syncthreads();
    #pragma unroll
    for (int i=0;i<4;++i){
      glds16(asrc[i] + kt*64, As + (wid*4+i)*512);
      glds16(bsrc[i] + kt*64, Bs + (wid*4+i)*512);
    }
    __syncthreads();
    #pragma unroll
    for (int kk=0;kk<2;++kk){
      bf16x8 af[4], bfr[4];
      const int s = kk*4 + sgrp;
      #pragma unroll
      for (int mi=0;mi<4;++mi){
        int R = wr + mi*16 + lr;
        af[mi] = *(const bf16x8*)&As[R*64 + ((s ^ (R & 7)) << 3)];
      }
      #pragma unroll
      for (int ni=0;ni<4;++ni){
        int Cc = wc + ni*16 + lr;
        bfr[ni] = *(const bf16x8*)&Bs[Cc*64 + ((s ^ (Cc & 7)) << 3)];
      }
      #pragma unroll
      for (int mi=0;mi<4;++mi)
        #pragma unroll
        for (int ni=0;ni<4;++ni)
          acc[mi][ni] = __builtin_amdgcn_mfma_f32_16x16x32_bf16(af[mi], bfr[ni], acc[mi][ni], 0, 0, 0);
    }
  }
  #pragma unroll
  for (int ni=0;ni<4;++ni){
    const int col = wc + ni*16 + lr;
    const float bv_ = b2[(size_t)e*128 + col];
    const int ch = col >> 3, cl = col & 7;
    #pragma unroll
    for (int mi=0;mi<4;++mi){
      #pragma unroll
      for (int q=0;q<4;++q){
        const int row = wr + mi*16 + sgrp*4 + q;
        float v = fmaxf(acc[mi][ni][q] + bv_, 0.f);
        Zs[row*128 + ((ch ^ (row & 15)) << 3) + cl] = f2bf(v);
      }
    }
  }
  __syncthreads();

  bf16x8 afk[4][4];
  #pragma unroll
  for (int kk=0;kk<4;++kk)
    #pragma unroll
    for (int mi=0;mi<4;++mi){
      int R = wr + mi*16 + lr;
      afk[kk][mi] = *(const bf16x8*)&Zs[R*128 + (((kk*4+sgrp) ^ (R & 15)) << 3)];
    }

  #pragma unroll 1
  for (int nt=0; nt<4; ++nt){
    #pragma unroll
    for (int i=0;i<8;++i){
      int R = (wid*8 + i)*4 + (lane >> 4);
      int sch = (lane & 15) ^ (R & 15);
      glds16(W3 + ((size_t)e*512 + nt*128 + R)*128 + sch*8, un + (size_t)(wid*8+i)*512);
    }
    __syncthreads();

    #pragma unroll
    for (int mi=0;mi<4;++mi)
      #pragma unroll
      for (int ni=0;ni<4;++ni) acc[mi][ni] = z4;

    #pragma unroll
    for (int kk=0;kk<4;++kk){
      bf16x8 bfr[4];
      const int s = kk*4 + sgrp;
      #pragma unroll
      for (int ni=0;ni<4;++ni){
        int Cc = wc + ni*16 + lr;
        bfr[ni] = *(const bf16x8*)&un[Cc*128 + ((s ^ (Cc & 15)) << 3)];
      }
      #pragma unroll
      for (int mi=0;mi<4;++mi)
        #pragma unroll
        for (int ni=0;ni<4;++ni)
          acc[mi][ni] = __builtin_amdgcn_mfma_f32_16x16x32_bf16(afk[kk][mi], bfr[ni], acc[mi][ni], 0, 0, 0);
    }
    __syncthreads();

    #pragma unroll
    for (int ni=0;ni<4;++ni){
      const int col = wc + ni*16 + lr;
      const float bv_ = b3[(size_t)e*512 + nt*128 + col];
      #pragma unroll
      for (int mi=0;mi<4;++mi){
        #pragma unroll
        for (int q=0;q<4;++q){
          const int row = wr + mi*16 + sgrp*4 + q;
          float v = fmaxf(acc[mi][ni][q] + bv_, 0.f);
          un[row*136 + col] = f2bf(v);
        }
      }
    }
    __syncthreads();
    #pragma unroll
    for (int i=0;i<8;++i){
      int idx = t + 256*i;
      int r = idx >> 4, c8 = idx & 15;
      *(uint4*)&D[(size_t)(row0 + r)*512 + nt*128 + c8*8] = *(const uint4*)&un[r*136 + c8*8];
    }
    __syncthreads();
  }
}

extern "C" void kernel_launch(void* const* d_in, const int* in_sizes, int n_in,
                              void* d_out, int out_size, void* d_ws, size_t ws_size,
                              hipStream_t stream) {
  const float* X   = (const float*)d_in[0];
  const int*   sym = (const int*)  d_in[1];
  const float* We1 = (const float*)d_in[2];
  const float* be1 = (const float*)d_in[3];
  const float* We2 = (const float*)d_in[4];
  const float* be2 = (const float*)d_in[5];
  const float* Wd1 = (const float*)d_in[6];
  const float* bd1 = (const float*)d_in[7];
  const float* Wd2 = (const float*)d_in[8];
  const float* bd2 = (const float*)d_in[9];
  float* out = (float*)d_out;

  char* ws = (char*)d_ws;
  int* hdr  = (int*)(ws + WS_HDR);
  int* perm = (int*)(ws + WS_PERM);
  int* bc   = (int*)(ws + WS_BC);
  int* bb   = (int*)(ws + WS_BB);
  unsigned short* W1t = (unsigned short*)(ws + WS_W1T);
  unsigned short* W2t = (unsigned short*)(ws + WS_W2T);
  unsigned short* W3t = (unsigned short*)(ws + WS_W3T);
  unsigned short* W4t = (unsigned short*)(ws + WS_W4T);
  unsigned short* H   = (unsigned short*)(ws + WS_H);
  unsigned short* Dd  = (unsigned short*)(ws + WS_D);   // aliases H
  unsigned short* Xb  = (unsigned short*)(ws + WS_XB);

  dim3 b256(256), b512(512), b1024(1024);
  routeA<<<dim3(128), b256, 0, stream>>>(sym, bc, perm);
  routeB<<<dim3(1), dim3(64), 0, stream>>>(bc, hdr, bb);
  // merged: scatter (32 blocks) || X convert || weight transposes
  prep_kernel<<<dim3(SCAT + XCONV + 512 + 64 + 64 + 512), b1024, 0, stream>>>(
      sym, bb, perm, X, Xb, We1, W1t, We2, W2t, Wd1, W3t, Wd2, W4t);

  // L1: relu(Xb[perm] @ We1 + be1) -> H   (gathered glds, 256x128, 8 waves)
  gemm_big<1024, 512, 4, true,  true,  false><<<dim3(MGRP*8*4), b512, 0, stream>>>(
      Xb, W1t, be1, H, nullptr, hdr, perm);
  // L2+L3 fused
  fused_mid<<<dim3(MB128), b256, 0, stream>>>(H, W2t, be2, W3t, bd1, Dd, hdr);
  // L4: scatter fp32 rows to out via perm
  gemm_big< 512,1024, 8, false, false, true ><<<dim3(MGRP*8*8), b512, 0, stream>>>(
      Dd, W4t, bd2, nullptr, out, hdr, perm);
}